// Round 5
// baseline (298.621 us; speedup 1.0000x reference)
//
#include <hip/hip_runtime.h>
#include <cstddef>

// RNN h_t = tanh(x_t W_ih^T + b + h_{t-1} W_hh^T), return h_T. B=4096,T=512,IN=15,H=20.
//
// R4: MFMA recurrence. Per wave: 16 batches. D = W_hh * H^T + Xp via two
// independent v_mfma_f32_16x16x32_f16 (M rows 0..15 and 16..19+pad; K=32
// holds hidden 20 + zero pad; N=16 batches). D layout (m89/m91): col=lane&15,
// row=4q+reg (q=lane>>4). tanh on 8 f32/lane, repack to f16, and rebuild the
// next step's B operand (n=lane&15, k=q*8+i) with 6 ds_bpermute using STATIC
// per-lane addresses (garbage slots hit zeroed A columns -> no masking).
// Xp precomputed per 8-step chunk by the same MFMA shape (A=W_ih, bias in C)
// from register-prefetched global loads. ZERO LDS in the kernel.
// 256 blocks x 64 threads (1 wave each).

typedef float g4 __attribute__((ext_vector_type(4), aligned(4)));
typedef float v4f __attribute__((ext_vector_type(4)));
typedef _Float16 v8h __attribute__((ext_vector_type(8)));
typedef int vi4 __attribute__((ext_vector_type(4)));

#define TT 512
#define IN 15
#define HD 20
#define CH 8
#define NCH (TT / CH)   // 64

#define MFMA16(a, b, c) __builtin_amdgcn_mfma_f32_16x16x32_f16(a, b, c, 0, 0, 0)

__device__ __forceinline__ int pk(float lo, float hi) {
  return __builtin_bit_cast(int, __builtin_amdgcn_cvt_pkrtz(lo, hi));
}
__device__ __forceinline__ float tanh_fast(float s) {
  // tanh(s) = 1 - 2/(1+e^{2s}); e^{2s} = exp2(s*2*log2(e)). v_exp + v_rcp.
  float e = exp2f(s * 2.8853900817779268f);
  return __builtin_fmaf(__builtin_amdgcn_rcpf(1.f + e), -2.f, 1.f);
}

__global__ __launch_bounds__(64, 1) void rnn_mfma(
    const float* __restrict__ feature, const float* __restrict__ W_ih,
    const float* __restrict__ W_hh, const float* __restrict__ b_ih,
    const float* __restrict__ b_hh, float* __restrict__ out) {
  const int lane = threadIdx.x;
  const int n = lane & 15;          // batch col within tile / A row m
  const int q = lane >> 4;          // k-group for A/B, row-group for C/D
  const bool qodd = (q & 1) != 0;
  const bool isQ2 = (q == 2);
  const int b = blockIdx.x * 16 + n;

  // ---- static A operands (f16 pairs), K index k = q*8 + 2d (+1) ----
  vi4 A1i, A2i, Xai, Xbi;
  {
    const int k0 = q * 8;
#pragma unroll
    for (int d = 0; d < 4; ++d) {
      const int k = k0 + 2 * d;
      const float w0 = (k < HD) ? W_hh[n * HD + k] : 0.f;
      const float w1 = (k + 1 < HD) ? W_hh[n * HD + k + 1] : 0.f;
      A1i[d] = pk(w0, w1);
      const float v0 = (n < 4 && k < HD) ? W_hh[(16 + n) * HD + k] : 0.f;
      const float v1 = (n < 4 && k + 1 < HD) ? W_hh[(16 + n) * HD + k + 1] : 0.f;
      A2i[d] = pk(v0, v1);
      const float x0 = (k < IN) ? W_ih[n * IN + k] : 0.f;
      const float x1 = (k + 1 < IN) ? W_ih[n * IN + k + 1] : 0.f;
      Xai[d] = pk(x0, x1);
      const float y0 = (n < 4 && k < IN) ? W_ih[(16 + n) * IN + k] : 0.f;
      const float y1 = (n < 4 && k + 1 < IN) ? W_ih[(16 + n) * IN + k + 1] : 0.f;
      Xbi[d] = pk(y0, y1);
    }
  }
  const v8h A1 = __builtin_bit_cast(v8h, A1i);
  const v8h A2 = __builtin_bit_cast(v8h, A2i);
  const v8h Xa = __builtin_bit_cast(v8h, Xai);
  const v8h Xb = __builtin_bit_cast(v8h, Xbi);

  // bias C tiles (C/D row = 4q+r)
  v4f Cba, Cbb;
#pragma unroll
  for (int r = 0; r < 4; ++r) {
    const int j = 4 * q + r;
    Cba[r] = b_ih[j] + b_hh[j];
    Cbb[r] = (q == 0) ? (b_ih[16 + r] + b_hh[16 + r]) : 0.f;
  }

  // ---- static bpermute byte-addresses for the D->B permutation ----
  // B dword d0/d1 src: q0<-self, q1<-(n+32), q2<-E at lane n;  d2/d3: +16.
  const int a0 = 4 * (n + ((q == 1) ? 32 : 0));
  const int a2 = 4 * (n + 16 + ((q == 1) ? 32 : 0));
  const int aE = 4 * n;

  // ---- feature prefetch (registers, no LDS). qeven: f0..7, qodd: f7..14 ----
  const float* fbase = feature + ((size_t)b * TT) * IN + (qodd ? 7 : 0);
  g4 flo[CH], fhi[CH];
  auto issueF = [&](int t0) {
#pragma unroll
    for (int tt = 0; tt < CH; ++tt) {
      const float* s = fbase + (size_t)(t0 + tt) * IN;
      flo[tt] = *(const g4*)s;
      fhi[tt] = *(const g4*)(s + 4);
    }
  };

  // ---- xp phase: xp tiles for one chunk via MFMA (bias folded in C) ----
  v4f xpa[CH], xpb[CH];
  auto doXP = [&]() {
#pragma unroll
    for (int tt = 0; tt < CH; ++tt) {
      const g4 lo = flo[tt], hi = fhi[tt];
      // B_x pairs: qeven (f0f1)(f2f3)(f4f5)(f6f7); qodd (f8f9)(f10f11)(f12f13)(f14,0)
      const int d0 = qodd ? pk(lo.y, lo.z) : pk(lo.x, lo.y);
      const int d1 = qodd ? pk(lo.w, hi.x) : pk(lo.z, lo.w);
      const int d2 = qodd ? pk(hi.y, hi.z) : pk(hi.x, hi.y);
      const int d3 = qodd ? pk(hi.w, 0.f) : pk(hi.z, hi.w);
      const v8h Bx = __builtin_bit_cast(v8h, (vi4){d0, d1, d2, d3});
      xpa[tt] = MFMA16(Xa, Bx, Cba);   // rows 0..15 (k>=15 cols of Xa are 0)
      xpb[tt] = MFMA16(Xb, Bx, Cbb);   // rows 16..19 (q0), else 0
    }
  };

  issueF(0);
  doXP();

  vi4 Bi = {0, 0, 0, 0};   // h0 = 0
  float T0 = 0.f, T1 = 0.f, T2 = 0.f, T3 = 0.f;
  float U0 = 0.f, U1 = 0.f, U2 = 0.f, U3 = 0.f;

  for (int c = 0; c < NCH; ++c) {
    if (c + 1 < NCH) issueF((c + 1) * CH);   // prefetch next chunk's feature
#pragma unroll
    for (int tt = 0; tt < CH; ++tt) {
      const v8h B = __builtin_bit_cast(v8h, Bi);
      const v4f Da = MFMA16(A1, B, xpa[tt]);   // rows 4q+r (j 0..15)
      const v4f Db = MFMA16(A2, B, xpb[tt]);   // rows 16+4q+r (real only q0)
      T0 = tanh_fast(Da.x); T1 = tanh_fast(Da.y);
      T2 = tanh_fast(Da.z); T3 = tanh_fast(Da.w);
      U0 = tanh_fast(Db.x); U1 = tanh_fast(Db.y);
      U2 = tanh_fast(Db.z); U3 = tanh_fast(Db.w);
      const int P0 = pk(T0, T1), P1 = pk(T2, T3);   // (T4q,T4q+1),(T4q+2,T4q+3)
      const int E0 = pk(U0, U1), E1 = pk(U2, U3);   // q0: (T16,T17),(T18,T19)
      const int g0 = __builtin_amdgcn_ds_bpermute(a0, P0);
      const int g0e = __builtin_amdgcn_ds_bpermute(aE, E0);
      const int g1 = __builtin_amdgcn_ds_bpermute(a0, P1);
      const int g1e = __builtin_amdgcn_ds_bpermute(aE, E1);
      const int d2 = __builtin_amdgcn_ds_bpermute(a2, P0);
      const int d3 = __builtin_amdgcn_ds_bpermute(a2, P1);
      // q3 / high-k slots carry finite garbage -> multiplied by zeroed A cols.
      Bi = (vi4){isQ2 ? g0e : g0, isQ2 ? g1e : g1, d2, d3};
    }
    if (c + 1 < NCH) doXP();   // compute next chunk's xp from prefetched regs
  }

  // ---- store h_T: lane (n,q) owns rows 4q..4q+3; q0 also rows 16..19 ----
  float* ob = out + (size_t)b * HD + 4 * q;
  ob[0] = T0; ob[1] = T1; ob[2] = T2; ob[3] = T3;
  if (q == 0) {
    float* o2 = out + (size_t)b * HD + 16;
    o2[0] = U0; o2[1] = U1; o2[2] = U2; o2[3] = U3;
  }
}

extern "C" void kernel_launch(void* const* d_in, const int* in_sizes, int n_in,
                              void* d_out, int out_size, void* d_ws, size_t ws_size,
                              hipStream_t stream) {
  const float* feature = (const float*)d_in[0];
  const float* W_ih    = (const float*)d_in[1];
  const float* W_hh    = (const float*)d_in[2];
  const float* b_ih    = (const float*)d_in[3];
  const float* b_hh    = (const float*)d_in[4];
  float* out = (float*)d_out;
  const int B = in_sizes[0] / (TT * IN);   // 4096
  rnn_mfma<<<B / 16, 64, 0, stream>>>(feature, W_ih, W_hh, b_ih, b_hh, out);
}

// Round 6
// 286.276 us; speedup vs baseline: 1.0431x; 1.0431x over previous
//
#include <hip/hip_runtime.h>
#include <cstddef>

// RNN h_t = tanh(x_t W_ih^T + b + h_{t-1} W_hh^T), return h_T. B=4096,T=512,IN=15,H=20.
//
// Round history: R1 (103us) = R0 mapping + f16 DS plane: 483 cyc/step, bound
// by 6 DS insts/step + coarse lgkm waits. R3-DPP (125us): DPP fmac = 1 MAC/
// inst, ~4.6 cyc each -> issue-bound. R4-MFMA (166us): 16 batches/wave -> 256
// waves = 0.25 waves/SIMD, everything latency-exposed (Occ 2.9%).
// R5 = R1 mapping (lane=(g,j), 3 batches per 64-thread 1-wave block, 1366
// waves) with x/xp moved OFF the DS pipe:
//  - each lane loads its group's 60B feature row straight from global
//    (same addr across group -> 1 line; L3-resident; VMEM pipe) with a
//    4-step prefetch ring in registers;
//  - xp computed inline (8 fdot2, f16) -- independent of h, fills the
//    ds_read latency shadow;
//  - DS per step: 3 broadcast h-reads (b128,b128,b64) + 1 b16 h-write, rows
//    48B apart -> bases at banks 0,12,24,4, conflict-free; no barriers
//    (single-wave workgroup, DS is in-order per wave).

typedef float g4 __attribute__((ext_vector_type(4), aligned(4)));
typedef __fp16 h2t __attribute__((ext_vector_type(2)));
typedef __fp16 v8h __attribute__((ext_vector_type(8)));
typedef __fp16 v4h __attribute__((ext_vector_type(4)));

#define TT 512
#define IN 15
#define HD 20
#define PF 4               // prefetch distance (steps); 4x16 f32 ring = 64 VGPR

#define PK(a, b) __builtin_amdgcn_cvt_pkrtz((a), (b))
#define FD(acc, p, w) acc = __builtin_amdgcn_fdot2((p), (w), (acc), false)
// constant-index f16 pair extract (frontend-constant under full unroll)
#define SH(v, i) __builtin_shufflevector((v), (v), 2 * (i), 2 * (i) + 1)

__device__ __forceinline__ float tanh_fast(float s) {
  // tanh(s) = 1 - 2/(1+e^{2s}); e^{2s} = exp2(s*2*log2 e). v_exp + v_rcp.
  const float e = exp2f(s * 2.8853900817779268f);
  return __builtin_fmaf(__builtin_amdgcn_rcpf(1.f + e), -2.f, 1.f);
}

__global__ __launch_bounds__(64, 1) void rnn_v5(
    const float* __restrict__ feature, const float* __restrict__ W_ih,
    const float* __restrict__ W_hh, const float* __restrict__ b_ih,
    const float* __restrict__ b_hh, float* __restrict__ out, int B) {
  __shared__ __fp16 hl[4 * 24];     // 4 h rows (row 3 = spill lanes 60..63)

  const int lane = threadIdx.x;
  const int g = lane / HD;          // 0..3
  const int j = lane - g * HD;      // 0..19
  const int b = blockIdx.x * 3 + g;
  const int bck = min(b, B - 1);    // clamp for loads (g==3 / tail)

  if (lane < 48) ((float*)hl)[lane] = 0.f;   // h0 = 0, all rows (96 halves)

  // per-lane weight rows as f16 pairs
  h2t wih[8];
  {
    const float* wr = W_ih + j * IN;
#pragma unroll
    for (int i = 0; i < 7; ++i) wih[i] = PK(wr[2 * i], wr[2 * i + 1]);
    wih[7] = PK(wr[14], 0.f);      // pairs with the zero in p7
  }
  h2t whh[10];
  {
    const float* wq = W_hh + j * HD;
#pragma unroll
    for (int i = 0; i < 10; ++i) whh[i] = PK(wq[2 * i], wq[2 * i + 1]);
  }
  const float bias = b_ih[j] + b_hh[j];

  const float* rb = feature + (size_t)bck * TT * IN;

  // prefetch ring: 4 slots x one 15-f32 row (loaded as 3x b128 + b128@44B)
  g4 xs[PF][4];
#pragma unroll
  for (int p = 0; p < PF; ++p) {
    const float* s = rb + (size_t)p * IN;
    xs[p][0] = *(const g4*)s;       xs[p][1] = *(const g4*)(s + 4);
    xs[p][2] = *(const g4*)(s + 8); xs[p][3] = *(const g4*)(s + 11);
  }

  const __fp16* hr = hl + g * 24;
  __fp16* hw = hl + g * 24 + j;
  float hn = 0.f;

#pragma unroll 1
  for (int it = 0; it < TT / PF; ++it) {
#pragma unroll
    for (int p = 0; p < PF; ++p) {
      const int t = it * PF + p;
      // h row reads first (broadcast; lgkm wait lands before the h dots)
      const v8h hA = *(const v8h*)hr;          // h0..7
      const v8h hB = *(const v8h*)(hr + 8);    // h8..15
      const v4h hC = *(const v4h*)(hr + 16);   // h16..19
      // consume prefetched x for step t
      const g4 x0 = xs[p][0], x1 = xs[p][1], x2 = xs[p][2], x3 = xs[p][3];
      // reload slot for step t+PF (clamped; garbage never consumed)
      {
        int tn = t + PF; tn = (tn < TT) ? tn : (TT - 1);
        const float* s = rb + (size_t)tn * IN;
        xs[p][0] = *(const g4*)s;       xs[p][1] = *(const g4*)(s + 4);
        xs[p][2] = *(const g4*)(s + 8); xs[p][3] = *(const g4*)(s + 11);
      }
      // xp inline: 8 pk + 8 fdot2 -- independent of h, fills ds-wait shadow
      const h2t p0 = PK(x0.x, x0.y), p1 = PK(x0.z, x0.w);
      const h2t p2 = PK(x1.x, x1.y), p3 = PK(x1.z, x1.w);
      const h2t p4 = PK(x2.x, x2.y), p5 = PK(x2.z, x2.w);   // (f10,f11)
      const h2t p6 = PK(x3.y, x3.z), p7 = PK(x3.w, 0.f);    // (f12,f13),(f14,0)
      float a0 = bias, a1 = 0.f;
      FD(a0, p0, wih[0]); FD(a1, p1, wih[1]);
      FD(a0, p2, wih[2]); FD(a1, p3, wih[3]);
      FD(a0, p4, wih[4]); FD(a1, p5, wih[5]);
      FD(a0, p6, wih[6]); FD(a1, p7, wih[7]);
      // recurrent dots: 10 fdot2, 2 chains of 5
      float b0 = 0.f, b1 = 0.f;
      FD(b0, SH(hA, 0), whh[0]); FD(b1, SH(hA, 1), whh[1]);
      FD(b0, SH(hA, 2), whh[2]); FD(b1, SH(hA, 3), whh[3]);
      FD(b0, SH(hB, 0), whh[4]); FD(b1, SH(hB, 1), whh[5]);
      FD(b0, SH(hB, 2), whh[6]); FD(b1, SH(hB, 3), whh[7]);
      FD(b0, SH(hC, 0), whh[8]); FD(b1, SH(hC, 1), whh[9]);
      hn = tanh_fast((a0 + a1) + (b0 + b1));
      *hw = (__fp16)hn;   // b16 write; same-wave DS in-order -> no barrier
    }
  }
  if (g < 3 && b < B) out[(size_t)b * HD + j] = hn;
}

extern "C" void kernel_launch(void* const* d_in, const int* in_sizes, int n_in,
                              void* d_out, int out_size, void* d_ws, size_t ws_size,
                              hipStream_t stream) {
  const float* feature = (const float*)d_in[0];
  const float* W_ih    = (const float*)d_in[1];
  const float* W_hh    = (const float*)d_in[2];
  const float* b_ih    = (const float*)d_in[3];
  const float* b_hh    = (const float*)d_in[4];
  float* out = (float*)d_out;
  const int B = in_sizes[0] / (TT * IN);   // 4096
  const int grid = (B + 2) / 3;            // 1366 single-wave blocks
  rnn_v5<<<grid, 64, 0, stream>>>(feature, W_ih, W_hh, b_ih, b_hh, out, B);
}

// Round 7
// 280.206 us; speedup vs baseline: 1.0657x; 1.0217x over previous
//
#include <hip/hip_runtime.h>
#include <cstddef>

// RNN h_t = tanh(x_t W_ih^T + b + h_{t-1} W_hh^T), return h_T. B=4096,T=512,IN=15,H=20.
//
// Model (R0-R5): wall = 512 * max(DS/CU, issue/SIMD, chain).
//   R1 103us = 483 cyc/step ~ DS-throughput (6 DS ops * 5.33 waves/CU).
//   R3 DPP: 1 MAC/inst, ~5cyc issue -> issue-bound. R4 MFMA: 256 waves ->
//   latency-exposed. R5: compiler collapsed the reg ring, loads sank into
//   the chain -> VMEM latency in-chain.
// R6: 2 hidden units per lane, 10 lanes/batch, 6 batches/wave (683 waves,
// 2.67/CU). Recurrent-step DS = 3 broadcast h reads (b128,b128,b64) + ONE
// packed ds_write_b32 (pair 2i,2i+1) -> DS/CU ~ 120 cyc. xp computed into
// REGISTERS per 8-step chunk (R4's phase structure, which held up), so no
// x traffic on the DS pipe and no VMEM in the chain. h rows stride 12
// dwords: bases {0,12,24,4,16,28,8} mod 32 -> all 3 read ops conflict-free.
// Single-wave blocks: same-wave DS is in-order -> no barriers; write->read
// round trip ~ one DS latency.

typedef float g4 __attribute__((ext_vector_type(4), aligned(4)));
typedef float v2f __attribute__((ext_vector_type(2)));
typedef __fp16 h2t __attribute__((ext_vector_type(2)));
typedef __fp16 v8h __attribute__((ext_vector_type(8)));
typedef __fp16 v4h __attribute__((ext_vector_type(4)));

#define TT 512
#define IN 15
#define HD 20
#define CH 8                 // chunk steps; x ring = CH*4 g4-quarters = 32 VGPR
#define NCH (TT / CH)        // 64
#define HROWH 24             // halves per h row (12 dwords)

#define PK(a, b) __builtin_amdgcn_cvt_pkrtz((a), (b))
#define FD(acc, p, w) acc = __builtin_amdgcn_fdot2((p), (w), (acc), false)
#define SH(v, i) __builtin_shufflevector((v), (v), 2 * (i), 2 * (i) + 1)

__device__ __forceinline__ float tanh_fast(float s) {
  // tanh(s) = 1 - 2/(1+e^{2s}); e^{2s} = exp2(s*2*log2 e)
  const float e = exp2f(s * 2.8853900817779268f);
  return __builtin_fmaf(__builtin_amdgcn_rcpf(1.f + e), -2.f, 1.f);
}

__global__ __launch_bounds__(64, 1) void rnn_v6(
    const float* __restrict__ feature, const float* __restrict__ W_ih,
    const float* __restrict__ W_hh, const float* __restrict__ b_ih,
    const float* __restrict__ b_hh, float* __restrict__ out, int B) {
  __shared__ __fp16 hl[7 * HROWH];   // rows 0..5 = batches, row 6 = idle lanes

  const int lane = threadIdx.x;
  const int g = lane / 10;           // 0..6 (6 = idle lanes 60..63)
  const int i = lane - g * 10;       // 0..9 ; lane owns units 2i, 2i+1
  const int b = blockIdx.x * 6 + g;
  const int bck = min(b, B - 1);

  if (lane < 84) ((float*)hl)[lane] = 0.f;   // zero all 7 rows (84 dwords)

  // per-lane weight rows (units u0=2i, u1=2i+1) as f16 pairs
  h2t wih0[8], wih1[8], whh0[10], whh1[10];
  {
    const float* r0 = W_ih + (2 * i) * IN;
    const float* r1 = r0 + IN;
#pragma unroll
    for (int p = 0; p < 7; ++p) {
      wih0[p] = PK(r0[2 * p], r0[2 * p + 1]);
      wih1[p] = PK(r1[2 * p], r1[2 * p + 1]);
    }
    wih0[7] = PK(r0[14], 0.f);
    wih1[7] = PK(r1[14], 0.f);
    const float* q0 = W_hh + (2 * i) * HD;
    const float* q1 = q0 + HD;
#pragma unroll
    for (int p = 0; p < 10; ++p) {
      whh0[p] = PK(q0[2 * p], q0[2 * p + 1]);
      whh1[p] = PK(q1[2 * p], q1[2 * p + 1]);
    }
  }
  const float bias0 = b_ih[2 * i] + b_hh[2 * i];
  const float bias1 = b_ih[2 * i + 1] + b_hh[2 * i + 1];

  // --- x chunk ring (registers): CH rows of 15 f32, loaded as 4x b128
  // (offsets 0,4,8,11 floats; overlap at 11 is harmless). Group-broadcast
  // addresses (10 lanes same row) -> coalesced to one line per group.
  const float* rb = feature + (size_t)bck * TT * IN;
  g4 xr[CH][4];
  auto issueF = [&](int t0) {
#pragma unroll
    for (int tt = 0; tt < CH; ++tt) {
      const float* s = rb + (size_t)(t0 + tt) * IN;
      xr[tt][0] = *(const g4*)s;
      xr[tt][1] = *(const g4*)(s + 4);
      xr[tt][2] = *(const g4*)(s + 8);
      xr[tt][3] = *(const g4*)(s + 11);
    }
  };

  // --- xp phase: ring -> xp registers for one chunk (both units)
  float xpa[CH], xpb[CH];
  auto doXP = [&]() {
#pragma unroll
    for (int tt = 0; tt < CH; ++tt) {
      const g4 x0 = xr[tt][0], x1 = xr[tt][1], x2 = xr[tt][2], x3 = xr[tt][3];
      const h2t p0 = PK(x0.x, x0.y), p1 = PK(x0.z, x0.w);
      const h2t p2 = PK(x1.x, x1.y), p3 = PK(x1.z, x1.w);
      const h2t p4 = PK(x2.x, x2.y), p5 = PK(x2.z, x2.w);    // f8..f11
      const h2t p6 = PK(x3.y, x3.z), p7 = PK(x3.w, 0.f);     // f12,f13 / f14,0
      float a0 = bias0, a1 = 0.f, c0 = bias1, c1 = 0.f;
      FD(a0, p0, wih0[0]); FD(c0, p0, wih1[0]);
      FD(a1, p1, wih0[1]); FD(c1, p1, wih1[1]);
      FD(a0, p2, wih0[2]); FD(c0, p2, wih1[2]);
      FD(a1, p3, wih0[3]); FD(c1, p3, wih1[3]);
      FD(a0, p4, wih0[4]); FD(c0, p4, wih1[4]);
      FD(a1, p5, wih0[5]); FD(c1, p5, wih1[5]);
      FD(a0, p6, wih0[6]); FD(c0, p6, wih1[6]);
      FD(a1, p7, wih0[7]); FD(c1, p7, wih1[7]);
      xpa[tt] = a0 + a1;
      xpb[tt] = c0 + c1;
    }
  };

  issueF(0);
  doXP();

  const __fp16* hr = hl + g * HROWH;
  __fp16* hw = hl + g * HROWH + 2 * i;   // one b32 covers units 2i,2i+1
  float h0n = 0.f, h1n = 0.f;

  for (int c = 0; c < NCH; ++c) {
    if (c + 1 < NCH) issueF((c + 1) * CH);   // prefetch next chunk into ring
#pragma unroll
    for (int tt = 0; tt < CH; ++tt) {
      const v8h hA = *(const v8h*)hr;          // h0..7   (ds_read_b128)
      const v8h hB = *(const v8h*)(hr + 8);    // h8..15  (ds_read_b128)
      const v4h hC = *(const v4h*)(hr + 16);   // h16..19 (ds_read_b64)
      float a0 = xpa[tt], a1 = 0.f, c0 = xpb[tt], c1 = 0.f;
      // 20 fdot2, 4 chains of depth 5; both units share the h-pair extracts
      FD(a0, SH(hA, 0), whh0[0]); FD(c0, SH(hA, 0), whh1[0]);
      FD(a1, SH(hA, 1), whh0[1]); FD(c1, SH(hA, 1), whh1[1]);
      FD(a0, SH(hA, 2), whh0[2]); FD(c0, SH(hA, 2), whh1[2]);
      FD(a1, SH(hA, 3), whh0[3]); FD(c1, SH(hA, 3), whh1[3]);
      FD(a0, SH(hB, 0), whh0[4]); FD(c0, SH(hB, 0), whh1[4]);
      FD(a1, SH(hB, 1), whh0[5]); FD(c1, SH(hB, 1), whh1[5]);
      FD(a0, SH(hB, 2), whh0[6]); FD(c0, SH(hB, 2), whh1[6]);
      FD(a1, SH(hB, 3), whh0[7]); FD(c1, SH(hB, 3), whh1[7]);
      FD(a0, SH(hC, 0), whh0[8]); FD(c0, SH(hC, 0), whh1[8]);
      FD(a1, SH(hC, 1), whh0[9]); FD(c1, SH(hC, 1), whh1[9]);
      h0n = tanh_fast(a0 + a1);
      h1n = tanh_fast(c0 + c1);
      *(h2t*)hw = (h2t){(__fp16)h0n, (__fp16)h1n};   // one ds_write_b32
    }
    if (c + 1 < NCH) doXP();   // ring -> xp for chunk c+1 (vmcnt lands here)
  }

  if (g < 6 && b < B) {
    v2f o = {h0n, h1n};
    *(v2f*)(out + (size_t)b * HD + 2 * i) = o;   // 8B-aligned (2i even)
  }
}

extern "C" void kernel_launch(void* const* d_in, const int* in_sizes, int n_in,
                              void* d_out, int out_size, void* d_ws, size_t ws_size,
                              hipStream_t stream) {
  const float* feature = (const float*)d_in[0];
  const float* W_ih    = (const float*)d_in[1];
  const float* W_hh    = (const float*)d_in[2];
  const float* b_ih    = (const float*)d_in[3];
  const float* b_hh    = (const float*)d_in[4];
  float* out = (float*)d_out;
  const int B = in_sizes[0] / (TT * IN);   // 4096
  const int grid = (B + 5) / 6;            // 683 single-wave blocks
  rnn_v6<<<grid, 64, 0, stream>>>(feature, W_ih, W_hh, b_ih, b_hh, out, B);
}